// Round 1
// baseline (578.715 us; speedup 1.0000x reference)
//
#include <hip/hip_runtime.h>
#include <math.h>

#define N_SAMPLES 4
#define P_ELEMS   (96*96*96)        // 884736
#define P4        (P_ELEMS/4)       // 221184
#define NBINS     32
// weight = exp(-(x - k/31)^2 / (2*sigma^2)), sigma = 0.015625, 1/(2s^2) = 2048
// in bin units: xb = x*31, arg = (xb-k)^2 * 2048/961
#define WCOEF     (2048.0f/961.0f)

__device__ __forceinline__ void atomicMinF(float* addr, float val) {
    int* ai = (int*)addr;
    int old = __float_as_int(*addr);
    while (__int_as_float(old) > val) {
        int assumed = old;
        old = atomicCAS(ai, assumed, __float_as_int(val));
        if (old == assumed) break;
    }
}
__device__ __forceinline__ void atomicMaxF(float* addr, float val) {
    int* ai = (int*)addr;
    int old = __float_as_int(*addr);
    while (__int_as_float(old) < val) {
        int assumed = old;
        old = atomicCAS(ai, assumed, __float_as_int(val));
        if (old == assumed) break;
    }
}

// ws layout: mm[16] = {mn_t,mx_t,mn_s,mx_s} x4 samples ; hist[4*1024]
__global__ void init_kernel(float* mm, float* hist) {
    int t = threadIdx.x;
    for (int i = t; i < N_SAMPLES * 1024; i += 256) hist[i] = 0.0f;
    if (t < 16) mm[t] = (t & 1) ? -INFINITY : INFINITY;
}

__global__ void minmax_kernel(const float* __restrict__ tar,
                              const float* __restrict__ src,
                              float* __restrict__ mm) {
    int n = blockIdx.y;
    const float4* t4 = (const float4*)(tar + (size_t)n * P_ELEMS);
    const float4* s4 = (const float4*)(src + (size_t)n * P_ELEMS);
    float mnt = INFINITY, mxt = -INFINITY, mns = INFINITY, mxs = -INFINITY;
    for (int idx = blockIdx.x * blockDim.x + threadIdx.x; idx < P4;
         idx += gridDim.x * blockDim.x) {
        float4 tv = t4[idx];
        float4 sv = s4[idx];
        mnt = fminf(mnt, fminf(fminf(tv.x, tv.y), fminf(tv.z, tv.w)));
        mxt = fmaxf(mxt, fmaxf(fmaxf(tv.x, tv.y), fmaxf(tv.z, tv.w)));
        mns = fminf(mns, fminf(fminf(sv.x, sv.y), fminf(sv.z, sv.w)));
        mxs = fmaxf(mxs, fmaxf(fmaxf(sv.x, sv.y), fmaxf(sv.z, sv.w)));
    }
    // wave reduce (width 64)
    #pragma unroll
    for (int o = 32; o; o >>= 1) {
        mnt = fminf(mnt, __shfl_xor(mnt, o));
        mxt = fmaxf(mxt, __shfl_xor(mxt, o));
        mns = fminf(mns, __shfl_xor(mns, o));
        mxs = fmaxf(mxs, __shfl_xor(mxs, o));
    }
    __shared__ float red[4][4];
    int lane = threadIdx.x & 63, wid = threadIdx.x >> 6;
    if (lane == 0) { red[wid][0] = mnt; red[wid][1] = mxt; red[wid][2] = mns; red[wid][3] = mxs; }
    __syncthreads();
    if (threadIdx.x == 0) {
        float a = red[0][0], b = red[0][1], c = red[0][2], d = red[0][3];
        for (int w = 1; w < 4; w++) {
            a = fminf(a, red[w][0]); b = fmaxf(b, red[w][1]);
            c = fminf(c, red[w][2]); d = fmaxf(d, red[w][3]);
        }
        atomicMinF(&mm[n * 4 + 0], a);
        atomicMaxF(&mm[n * 4 + 1], b);
        atomicMinF(&mm[n * 4 + 2], c);
        atomicMaxF(&mm[n * 4 + 3], d);
    }
}

__global__ void __launch_bounds__(256)
hist_kernel(const float* __restrict__ tar, const float* __restrict__ src,
            const float* __restrict__ mm, float* __restrict__ hist) {
    int n = blockIdx.y;
    const float4* t4 = (const float4*)(tar + (size_t)n * P_ELEMS);
    const float4* s4 = (const float4*)(src + (size_t)n * P_ELEMS);
    float mnt = mm[n * 4 + 0], mxt = mm[n * 4 + 1];
    float mns = mm[n * 4 + 2], mxs = mm[n * 4 + 3];
    float invt = 31.0f / (mxt - mnt + 1e-12f);
    float invs = 31.0f / (mxs - mns + 1e-12f);

    __shared__ float h[4][NBINS * NBINS];   // per-wave private hist, 16 KB
    for (int i = threadIdx.x; i < 4 * NBINS * NBINS; i += 256) ((float*)h)[i] = 0.0f;
    __syncthreads();
    float* hw = h[threadIdx.x >> 6];

    for (int idx = blockIdx.x * blockDim.x + threadIdx.x; idx < P4;
         idx += gridDim.x * blockDim.x) {
        float4 tv = t4[idx];
        float4 sv = s4[idx];
        float te[4] = { tv.x, tv.y, tv.z, tv.w };
        float se[4] = { sv.x, sv.y, sv.z, sv.w };
        #pragma unroll
        for (int e = 0; e < 4; e++) {
            float xb = (te[e] - mnt) * invt;   // bin coordinate 0..31
            float yb = (se[e] - mns) * invs;
            int cx = (int)rintf(xb);
            int cy = (int)rintf(yb);
            float wt[5], ww[5];
            #pragma unroll
            for (int a = 0; a < 5; a++) {
                int k = cx - 2 + a;
                float d = xb - (float)k;
                float w = __expf(-WCOEF * d * d);
                wt[a] = ((unsigned)k < 32u) ? w : 0.0f;
                k = cy - 2 + a;
                d = yb - (float)k;
                w = __expf(-WCOEF * d * d);
                ww[a] = ((unsigned)k < 32u) ? w : 0.0f;
            }
            #pragma unroll
            for (int a = 0; a < 5; a++) {
                int ti = cx - 2 + a;
                float wa = wt[a];
                #pragma unroll
                for (int b = 0; b < 5; b++) {
                    float v = wa * ww[b];
                    if (v > 1e-7f) {
                        atomicAdd(&hw[ti * NBINS + (cy - 2 + b)], v);
                    }
                }
            }
        }
    }
    __syncthreads();
    for (int i = threadIdx.x; i < NBINS * NBINS; i += 256) {
        float v = h[0][i] + h[1][i] + h[2][i] + h[3][i];
        if (v != 0.0f) unsafeAtomicAdd(&hist[n * NBINS * NBINS + i], v);
    }
}

__device__ __forceinline__ float block_sum_1024(float v, float* red, float* bcast) {
    #pragma unroll
    for (int o = 32; o; o >>= 1) v += __shfl_xor(v, o);
    __syncthreads();                     // protect red from previous round
    int lane = threadIdx.x & 63, wid = threadIdx.x >> 6;
    if (lane == 0) red[wid] = v;
    __syncthreads();
    if (threadIdx.x == 0) {
        float s = 0.0f;
        for (int i = 0; i < 16; i++) s += red[i];
        *bcast = s;
    }
    __syncthreads();
    return *bcast;
}

__global__ void __launch_bounds__(1024)
finalize_kernel(const float* __restrict__ hist, float* __restrict__ out) {
    __shared__ float red[16];
    __shared__ float bcast;
    __shared__ float sh[NBINS * NBINS];
    __shared__ float rowcol[64];
    __shared__ float acc_s;
    int t = threadIdx.x;
    if (t == 0) acc_s = 0.0f;
    for (int n = 0; n < N_SAMPLES; n++) {
        float hval = hist[n * NBINS * NBINS + t];
        float norm = block_sum_1024(hval, red, &bcast);
        float p = hval / norm;
        sh[t] = p;
        float ej = block_sum_1024(-p * logf(p + 1e-10f), red, &bcast);
        // marginals (sh[] visible: block_sum has syncthreads after the write)
        if (t < 32) {
            float m = 0.0f;
            for (int j = 0; j < 32; j++) m += sh[t * 32 + j];
            rowcol[t] = -m * logf(m + 1e-10f);
        } else if (t < 64) {
            int j = t - 32;
            float m = 0.0f;
            for (int i = 0; i < 32; i++) m += sh[i * 32 + j];
            rowcol[t] = -m * logf(m + 1e-10f);
        }
        __syncthreads();
        if (t == 0) {
            float et = 0.0f, es = 0.0f;
            for (int i = 0; i < 32; i++) { et += rowcol[i]; es += rowcol[32 + i]; }
            acc_s += (et + es) / ej;
        }
        __syncthreads();
    }
    if (t == 0) out[0] = -acc_s * (1.0f / N_SAMPLES);
}

extern "C" void kernel_launch(void* const* d_in, const int* in_sizes, int n_in,
                              void* d_out, int out_size, void* d_ws, size_t ws_size,
                              hipStream_t stream) {
    const float* tar = (const float*)d_in[0];
    const float* src = (const float*)d_in[1];
    float* out = (float*)d_out;
    float* mm = (float*)d_ws;            // 16 floats
    float* hist = mm + 16;               // 4*1024 floats

    init_kernel<<<1, 256, 0, stream>>>(mm, hist);
    minmax_kernel<<<dim3(128, N_SAMPLES), 256, 0, stream>>>(tar, src, mm);
    hist_kernel<<<dim3(256, N_SAMPLES), 256, 0, stream>>>(tar, src, mm, hist);
    finalize_kernel<<<1, 1024, 0, stream>>>(hist, out);
}

// Round 2
// 182.695 us; speedup vs baseline: 3.1677x; 3.1677x over previous
//
#include <hip/hip_runtime.h>
#include <math.h>

#define N_SAMPLES 4
#define P_ELEMS   (96*96*96)        // 884736
#define P4        (P_ELEMS/4)       // 221184
#define NBINS     32
#define TILE      4096              // elements per block per sample
#define NBLK      (P_ELEMS / TILE)  // 216, exact
// weight = exp(-(xb-k)^2 * 2048/961) in bin units (xb = x*31), sigma = 1/64
#define WCOEF     (2048.0f/961.0f)
#define C2EXP     (-(2048.0f/961.0f) * 1.44269504089f)   // for exp2

typedef __attribute__((ext_vector_type(8)))  short short8;
typedef __attribute__((ext_vector_type(16))) float float16;

__device__ __forceinline__ void atomicMinF(float* addr, float val) {
    int* ai = (int*)addr;
    int old = __float_as_int(*addr);
    while (__int_as_float(old) > val) {
        int assumed = old;
        old = atomicCAS(ai, assumed, __float_as_int(val));
        if (old == assumed) break;
    }
}
__device__ __forceinline__ void atomicMaxF(float* addr, float val) {
    int* ai = (int*)addr;
    int old = __float_as_int(*addr);
    while (__int_as_float(old) < val) {
        int assumed = old;
        old = atomicCAS(ai, assumed, __float_as_int(val));
        if (old == assumed) break;
    }
}

// ws layout: mm[16] = {mn_t,mx_t,mn_s,mx_s} x4 samples ; hist[4*1024]
__global__ void init_kernel(float* mm, float* hist) {
    int t = threadIdx.x;
    for (int i = t; i < N_SAMPLES * 1024; i += 256) hist[i] = 0.0f;
    if (t < 16) mm[t] = (t & 1) ? -INFINITY : INFINITY;
}

__global__ void minmax_kernel(const float* __restrict__ tar,
                              const float* __restrict__ src,
                              float* __restrict__ mm) {
    int n = blockIdx.y;
    const float4* t4 = (const float4*)(tar + (size_t)n * P_ELEMS);
    const float4* s4 = (const float4*)(src + (size_t)n * P_ELEMS);
    float mnt = INFINITY, mxt = -INFINITY, mns = INFINITY, mxs = -INFINITY;
    for (int idx = blockIdx.x * blockDim.x + threadIdx.x; idx < P4;
         idx += gridDim.x * blockDim.x) {
        float4 tv = t4[idx];
        float4 sv = s4[idx];
        mnt = fminf(mnt, fminf(fminf(tv.x, tv.y), fminf(tv.z, tv.w)));
        mxt = fmaxf(mxt, fmaxf(fmaxf(tv.x, tv.y), fmaxf(tv.z, tv.w)));
        mns = fminf(mns, fminf(fminf(sv.x, sv.y), fminf(sv.z, sv.w)));
        mxs = fmaxf(mxs, fmaxf(fmaxf(sv.x, sv.y), fmaxf(sv.z, sv.w)));
    }
    #pragma unroll
    for (int o = 32; o; o >>= 1) {
        mnt = fminf(mnt, __shfl_xor(mnt, o));
        mxt = fmaxf(mxt, __shfl_xor(mxt, o));
        mns = fminf(mns, __shfl_xor(mns, o));
        mxs = fmaxf(mxs, __shfl_xor(mxs, o));
    }
    __shared__ float red[4][4];
    int lane = threadIdx.x & 63, wid = threadIdx.x >> 6;
    if (lane == 0) { red[wid][0] = mnt; red[wid][1] = mxt; red[wid][2] = mns; red[wid][3] = mxs; }
    __syncthreads();
    if (threadIdx.x == 0) {
        float a = red[0][0], b = red[0][1], c = red[0][2], d = red[0][3];
        for (int w = 1; w < 4; w++) {
            a = fminf(a, red[w][0]); b = fmaxf(b, red[w][1]);
            c = fminf(c, red[w][2]); d = fmaxf(d, red[w][3]);
        }
        atomicMinF(&mm[n * 4 + 0], a);
        atomicMaxF(&mm[n * 4 + 1], b);
        atomicMinF(&mm[n * 4 + 2], c);
        atomicMaxF(&mm[n * 4 + 3], d);
    }
}

// Joint histogram as a 32x32xK GEMM on the matrix cores.
// A[i][k] = gauss(xb[k], bin i), B[k][j] = gauss(yb[k], bin j).
// Lane (g=lane>>5, c=lane&31) provides A[c][8g+j] / B[8g+j][c], j=0..7 —
// so each lane evaluates 8 weights at its fixed bin c. exp2 underflow
// naturally zeroes far bins (exact dense reference, no truncation).
__global__ void __launch_bounds__(256)
hist_mfma(const float* __restrict__ tar, const float* __restrict__ src,
          const float* __restrict__ mm, float* __restrict__ hist) {
    __shared__ __align__(16) float lds[2 * TILE];   // xb[4096] | yb[4096], 32 KB
    int n = blockIdx.y;
    const float4* t4 = (const float4*)(tar + (size_t)n * P_ELEMS);
    const float4* s4 = (const float4*)(src + (size_t)n * P_ELEMS);
    float mnt = mm[n * 4 + 0], mxt = mm[n * 4 + 1];
    float mns = mm[n * 4 + 2], mxs = mm[n * 4 + 3];
    float invt = 31.0f / (mxt - mnt + 1e-12f);
    float invs = 31.0f / (mxs - mns + 1e-12f);

    // Stage: normalize to bin coordinates, write to LDS
    int base4 = blockIdx.x * (TILE / 4);
    #pragma unroll
    for (int r = 0; r < TILE / 4 / 256; r++) {      // 4 iterations
        int i4 = threadIdx.x + r * 256;
        float4 tv = t4[base4 + i4];
        float4 sv = s4[base4 + i4];
        float4 xo, yo;
        xo.x = (tv.x - mnt) * invt; xo.y = (tv.y - mnt) * invt;
        xo.z = (tv.z - mnt) * invt; xo.w = (tv.w - mnt) * invt;
        yo.x = (sv.x - mns) * invs; yo.y = (sv.y - mns) * invs;
        yo.z = (sv.z - mns) * invs; yo.w = (sv.w - mns) * invs;
        ((float4*)lds)[i4] = xo;
        ((float4*)(lds + TILE))[i4] = yo;
    }
    __syncthreads();

    int lane = threadIdx.x & 63;
    int wave = threadIdx.x >> 6;
    int g = lane >> 5;                  // K-half within the MFMA
    float cf = (float)(lane & 31);      // this lane's bin
    const float* xb = lds + wave * 1024;        // each wave owns 1024 elements
    const float* yb = lds + TILE + wave * 1024;

    float16 acc;
    #pragma unroll
    for (int i = 0; i < 16; i++) acc[i] = 0.0f;

    #pragma unroll 2
    for (int it = 0; it < 64; it++) {   // 16 elements per iteration
        int kb = it * 16 + g * 8;
        float4 xa = *(const float4*)(xb + kb);
        float4 xc = *(const float4*)(xb + kb + 4);
        float4 ya = *(const float4*)(yb + kb);
        float4 yc = *(const float4*)(yb + kb + 4);
        float xs[8] = {xa.x, xa.y, xa.z, xa.w, xc.x, xc.y, xc.z, xc.w};
        float ys[8] = {ya.x, ya.y, ya.z, ya.w, yc.x, yc.y, yc.z, yc.w};
        unsigned av[8], bv[8];
        #pragma unroll
        for (int j = 0; j < 8; j++) {
            float d = xs[j] - cf;
            float arg = d * d * C2EXP;
            float w;
            asm("v_exp_f32 %0, %1" : "=v"(w) : "v"(arg));
            av[j] = __float_as_uint(w);
            d = ys[j] - cf;
            arg = d * d * C2EXP;
            asm("v_exp_f32 %0, %1" : "=v"(w) : "v"(arg));
            bv[j] = __float_as_uint(w);
        }
        union { unsigned u[4]; short8 v; } af, bf;
        #pragma unroll
        for (int j = 0; j < 4; j++) {   // bf16 truncation pack (bias cancels in normalization)
            af.u[j] = (av[2 * j] >> 16) | (av[2 * j + 1] & 0xFFFF0000u);
            bf.u[j] = (bv[2 * j] >> 16) | (bv[2 * j + 1] & 0xFFFF0000u);
        }
        acc = __builtin_amdgcn_mfma_f32_32x32x16_bf16(af.v, bf.v, acc, 0, 0, 0);
    }

    // Each wave writes its 32x32 partial into its own (finished) xb slice.
    // C/D layout: col = lane&31, row = (reg&3) + 8*(reg>>2) + 4*(lane>>5).
    float* hw = lds + wave * 1024;
    int col = lane & 31;
    #pragma unroll
    for (int reg = 0; reg < 16; reg++) {
        int row = (reg & 3) + 8 * (reg >> 2) + 4 * g;
        hw[row * 32 + col] = acc[reg];
    }
    __syncthreads();
    for (int b = threadIdx.x; b < 1024; b += 256) {
        float v = lds[b] + lds[1024 + b] + lds[2048 + b] + lds[3072 + b];
        unsafeAtomicAdd(&hist[n * 1024 + b], v);
    }
}

__device__ __forceinline__ float block_sum_1024(float v, float* red, float* bcast) {
    #pragma unroll
    for (int o = 32; o; o >>= 1) v += __shfl_xor(v, o);
    __syncthreads();
    int lane = threadIdx.x & 63, wid = threadIdx.x >> 6;
    if (lane == 0) red[wid] = v;
    __syncthreads();
    if (threadIdx.x == 0) {
        float s = 0.0f;
        for (int i = 0; i < 16; i++) s += red[i];
        *bcast = s;
    }
    __syncthreads();
    return *bcast;
}

__global__ void __launch_bounds__(1024)
finalize_kernel(const float* __restrict__ hist, float* __restrict__ out) {
    __shared__ float red[16];
    __shared__ float bcast;
    __shared__ float sh[NBINS * NBINS];
    __shared__ float rowcol[64];
    __shared__ float acc_s;
    int t = threadIdx.x;
    if (t == 0) acc_s = 0.0f;
    for (int n = 0; n < N_SAMPLES; n++) {
        float hval = hist[n * NBINS * NBINS + t];
        float norm = block_sum_1024(hval, red, &bcast);
        float p = hval / norm;
        sh[t] = p;
        float ej = block_sum_1024(-p * __logf(p + 1e-10f), red, &bcast);
        if (t < 32) {
            float m = 0.0f;
            for (int j = 0; j < 32; j++) m += sh[t * 32 + j];
            rowcol[t] = -m * __logf(m + 1e-10f);
        } else if (t < 64) {
            int j = t - 32;
            float m = 0.0f;
            for (int i = 0; i < 32; i++) m += sh[i * 32 + j];
            rowcol[t] = -m * __logf(m + 1e-10f);
        }
        __syncthreads();
        if (t == 0) {
            float et = 0.0f, es = 0.0f;
            for (int i = 0; i < 32; i++) { et += rowcol[i]; es += rowcol[32 + i]; }
            acc_s += (et + es) / ej;
        }
        __syncthreads();
    }
    if (t == 0) out[0] = -acc_s * (1.0f / N_SAMPLES);
}

extern "C" void kernel_launch(void* const* d_in, const int* in_sizes, int n_in,
                              void* d_out, int out_size, void* d_ws, size_t ws_size,
                              hipStream_t stream) {
    const float* tar = (const float*)d_in[0];
    const float* src = (const float*)d_in[1];
    float* out = (float*)d_out;
    float* mm = (float*)d_ws;            // 16 floats
    float* hist = mm + 16;               // 4*1024 floats

    init_kernel<<<1, 256, 0, stream>>>(mm, hist);
    minmax_kernel<<<dim3(128, N_SAMPLES), 256, 0, stream>>>(tar, src, mm);
    hist_mfma<<<dim3(NBLK, N_SAMPLES), 256, 0, stream>>>(tar, src, mm, hist);
    finalize_kernel<<<1, 1024, 0, stream>>>(hist, out);
}

// Round 3
// 162.579 us; speedup vs baseline: 3.5596x; 1.1237x over previous
//
#include <hip/hip_runtime.h>
#include <math.h>

#define N_SAMPLES 4
#define P_ELEMS   (96*96*96)        // 884736
#define P4        (P_ELEMS/4)       // 221184 float4 per sample per array
#define NBINS     32
#define TILE      4096              // elements per block per sample (hist)
#define NBLK      (P_ELEMS / TILE)  // 216, exact
#define MMBLK     216               // minmax blocks per sample: 216*256*4 = 221184 float4, exact
// weight = exp(-(xb-k)^2 * 2048/961) in bin units (xb = x*31), sigma = 1/64
#define C2EXP     (-(2048.0f/961.0f) * 1.44269504089f)   // for exp2
#define EPSR      1e-10f

typedef __attribute__((ext_vector_type(8)))  short short8;
typedef __attribute__((ext_vector_type(16))) float float16;

// order-preserving float->uint key: min/max over keys == min/max over floats
__device__ __forceinline__ unsigned fkey(float f) {
    unsigned b = __float_as_uint(f);
    return (b & 0x80000000u) ? ~b : (b | 0x80000000u);
}
__device__ __forceinline__ float fkeydec(unsigned k) {
    unsigned b = (k & 0x80000000u) ? (k ^ 0x80000000u) : ~k;
    return __uint_as_float(b);
}

// ws layout: mmk[16] uint keys: [0..7]=min (n*2 + {tar,src}), [8..15]=max; then hist[4*1024] floats
__global__ void __launch_bounds__(256)
minmax_kernel(const float* __restrict__ tar, const float* __restrict__ src,
              unsigned* __restrict__ mmk) {
    int n = blockIdx.y;
    const float4* t4 = (const float4*)(tar + (size_t)n * P_ELEMS) + (size_t)blockIdx.x * 1024;
    const float4* s4 = (const float4*)(src + (size_t)n * P_ELEMS) + (size_t)blockIdx.x * 1024;
    int t = threadIdx.x;
    // 8 independent loads in flight
    float4 a0 = t4[t], a1 = t4[t + 256], a2 = t4[t + 512], a3 = t4[t + 768];
    float4 b0 = s4[t], b1 = s4[t + 256], b2 = s4[t + 512], b3 = s4[t + 768];
    float mnt = fminf(fminf(fminf(a0.x, a0.y), fminf(a0.z, a0.w)),
                      fminf(fminf(a1.x, a1.y), fminf(a1.z, a1.w)));
    mnt = fminf(mnt, fminf(fminf(fminf(a2.x, a2.y), fminf(a2.z, a2.w)),
                           fminf(fminf(a3.x, a3.y), fminf(a3.z, a3.w))));
    float mxt = fmaxf(fmaxf(fmaxf(a0.x, a0.y), fmaxf(a0.z, a0.w)),
                      fmaxf(fmaxf(a1.x, a1.y), fmaxf(a1.z, a1.w)));
    mxt = fmaxf(mxt, fmaxf(fmaxf(fmaxf(a2.x, a2.y), fmaxf(a2.z, a2.w)),
                           fmaxf(fmaxf(a3.x, a3.y), fmaxf(a3.z, a3.w))));
    float mns = fminf(fminf(fminf(b0.x, b0.y), fminf(b0.z, b0.w)),
                      fminf(fminf(b1.x, b1.y), fminf(b1.z, b1.w)));
    mns = fminf(mns, fminf(fminf(fminf(b2.x, b2.y), fminf(b2.z, b2.w)),
                           fminf(fminf(b3.x, b3.y), fminf(b3.z, b3.w))));
    float mxs = fmaxf(fmaxf(fmaxf(b0.x, b0.y), fmaxf(b0.z, b0.w)),
                      fmaxf(fmaxf(b1.x, b1.y), fmaxf(b1.z, b1.w)));
    mxs = fmaxf(mxs, fmaxf(fmaxf(fmaxf(b2.x, b2.y), fmaxf(b2.z, b2.w)),
                           fmaxf(fmaxf(b3.x, b3.y), fmaxf(b3.z, b3.w))));
    #pragma unroll
    for (int o = 32; o; o >>= 1) {
        mnt = fminf(mnt, __shfl_xor(mnt, o));
        mxt = fmaxf(mxt, __shfl_xor(mxt, o));
        mns = fminf(mns, __shfl_xor(mns, o));
        mxs = fmaxf(mxs, __shfl_xor(mxs, o));
    }
    __shared__ unsigned red[4][4];
    int lane = threadIdx.x & 63, wid = threadIdx.x >> 6;
    if (lane == 0) {
        red[wid][0] = fkey(mnt); red[wid][1] = fkey(mxt);
        red[wid][2] = fkey(mns); red[wid][3] = fkey(mxs);
    }
    __syncthreads();
    if (threadIdx.x == 0) {
        unsigned a = red[0][0], b = red[0][1], c = red[0][2], d = red[0][3];
        for (int w = 1; w < 4; w++) {
            a = min(a, red[w][0]); b = max(b, red[w][1]);
            c = min(c, red[w][2]); d = max(d, red[w][3]);
        }
        atomicMin(&mmk[n * 2 + 0], a);
        atomicMax(&mmk[8 + n * 2 + 0], b);
        atomicMin(&mmk[n * 2 + 1], c);
        atomicMax(&mmk[8 + n * 2 + 1], d);
    }
}

// Joint histogram as a 32x32xK GEMM on the matrix cores (see R2 notes).
__global__ void __launch_bounds__(256)
hist_mfma(const float* __restrict__ tar, const float* __restrict__ src,
          const unsigned* __restrict__ mmk, float* __restrict__ hist) {
    __shared__ __align__(16) float lds[2 * TILE];   // xb[4096] | yb[4096], 32 KB
    int n = blockIdx.y;
    const float4* t4 = (const float4*)(tar + (size_t)n * P_ELEMS);
    const float4* s4 = (const float4*)(src + (size_t)n * P_ELEMS);
    float mnt = fkeydec(mmk[n * 2 + 0]), mxt = fkeydec(mmk[8 + n * 2 + 0]);
    float mns = fkeydec(mmk[n * 2 + 1]), mxs = fkeydec(mmk[8 + n * 2 + 1]);
    float invt = 31.0f / (mxt - mnt + 1e-12f);
    float invs = 31.0f / (mxs - mns + 1e-12f);

    int base4 = blockIdx.x * (TILE / 4);
    #pragma unroll
    for (int r = 0; r < TILE / 4 / 256; r++) {      // 4 iterations
        int i4 = threadIdx.x + r * 256;
        float4 tv = t4[base4 + i4];
        float4 sv = s4[base4 + i4];
        float4 xo, yo;
        xo.x = (tv.x - mnt) * invt; xo.y = (tv.y - mnt) * invt;
        xo.z = (tv.z - mnt) * invt; xo.w = (tv.w - mnt) * invt;
        yo.x = (sv.x - mns) * invs; yo.y = (sv.y - mns) * invs;
        yo.z = (sv.z - mns) * invs; yo.w = (sv.w - mns) * invs;
        ((float4*)lds)[i4] = xo;
        ((float4*)(lds + TILE))[i4] = yo;
    }
    __syncthreads();

    int lane = threadIdx.x & 63;
    int wave = threadIdx.x >> 6;
    int g = lane >> 5;                  // K-half within the MFMA
    float cf = (float)(lane & 31);      // this lane's bin
    const float* xb = lds + wave * 1024;
    const float* yb = lds + TILE + wave * 1024;

    float16 acc;
    #pragma unroll
    for (int i = 0; i < 16; i++) acc[i] = 0.0f;

    #pragma unroll 2
    for (int it = 0; it < 64; it++) {   // 16 elements per iteration
        int kb = it * 16 + g * 8;
        float4 xa = *(const float4*)(xb + kb);
        float4 xc = *(const float4*)(xb + kb + 4);
        float4 ya = *(const float4*)(yb + kb);
        float4 yc = *(const float4*)(yb + kb + 4);
        float xs[8] = {xa.x, xa.y, xa.z, xa.w, xc.x, xc.y, xc.z, xc.w};
        float ys[8] = {ya.x, ya.y, ya.z, ya.w, yc.x, yc.y, yc.z, yc.w};
        unsigned av[8], bv[8];
        #pragma unroll
        for (int j = 0; j < 8; j++) {
            float d = xs[j] - cf;
            float arg = d * d * C2EXP;
            float w;
            asm("v_exp_f32 %0, %1" : "=v"(w) : "v"(arg));
            av[j] = __float_as_uint(w);
            d = ys[j] - cf;
            arg = d * d * C2EXP;
            asm("v_exp_f32 %0, %1" : "=v"(w) : "v"(arg));
            bv[j] = __float_as_uint(w);
        }
        union { unsigned u[4]; short8 v; } af, bf;
        #pragma unroll
        for (int j = 0; j < 4; j++) {   // bf16 truncation pack (bias cancels in normalization)
            af.u[j] = (av[2 * j] >> 16) | (av[2 * j + 1] & 0xFFFF0000u);
            bf.u[j] = (bv[2 * j] >> 16) | (bv[2 * j + 1] & 0xFFFF0000u);
        }
        acc = __builtin_amdgcn_mfma_f32_32x32x16_bf16(af.v, bf.v, acc, 0, 0, 0);
    }

    // C/D layout: col = lane&31, row = (reg&3) + 8*(reg>>2) + 4*(lane>>5).
    float* hw = lds + wave * 1024;
    int col = lane & 31;
    #pragma unroll
    for (int reg = 0; reg < 16; reg++) {
        int row = (reg & 3) + 8 * (reg >> 2) + 4 * g;
        hw[row * 32 + col] = acc[reg];
    }
    __syncthreads();
    for (int b = threadIdx.x; b < 1024; b += 256) {
        float v = lds[b] + lds[1024 + b] + lds[2048 + b] + lds[3072 + b];
        unsafeAtomicAdd(&hist[n * 1024 + b], v);
    }
}

// One wave per sample; shuffle-only reductions.
__global__ void __launch_bounds__(256)
finalize_kernel(const float* __restrict__ hist, float* __restrict__ out) {
    __shared__ float sh[N_SAMPLES][1024];
    __shared__ float waveres[N_SAMPLES];
    int lane = threadIdx.x & 63;
    int n = threadIdx.x >> 6;
    const float4* h4 = (const float4*)(hist + n * 1024);
    float4 h[4];
    float part = 0.0f;
    #pragma unroll
    for (int r = 0; r < 4; r++) {
        h[r] = h4[lane * 4 + r];                    // bins lane*16 .. lane*16+15
        part += (h[r].x + h[r].y) + (h[r].z + h[r].w);
    }
    #pragma unroll
    for (int o = 32; o; o >>= 1) part += __shfl_xor(part, o);
    float inv = 1.0f / part;
    float ej = 0.0f;
    #pragma unroll
    for (int r = 0; r < 4; r++) {
        float4 p;
        p.x = h[r].x * inv; p.y = h[r].y * inv; p.z = h[r].z * inv; p.w = h[r].w * inv;
        ((float4*)sh[n])[lane * 4 + r] = p;
        ej -= p.x * __logf(p.x + EPSR) + p.y * __logf(p.y + EPSR)
            + p.z * __logf(p.z + EPSR) + p.w * __logf(p.w + EPSR);
    }
    #pragma unroll
    for (int o = 32; o; o >>= 1) ej += __shfl_xor(ej, o);
    __syncthreads();
    // marginals: lanes 0..31 -> rows (skewed to dodge bank conflicts), 32..63 -> cols
    float m = 0.0f;
    if (lane < 32) {
        int row = lane;
        for (int j = 0; j < 32; j++) m += sh[n][row * 32 + ((j + row) & 31)];
    } else {
        int col = lane - 32;
        for (int i = 0; i < 32; i++) m += sh[n][i * 32 + col];
    }
    float rc = -m * __logf(m + EPSR);
    #pragma unroll
    for (int o = 16; o; o >>= 1) rc += __shfl_xor(rc, o);   // halves reduce separately
    float es = __shfl(rc, 32);
    if (lane == 0) waveres[n] = (rc + es) / ej;
    __syncthreads();
    if (threadIdx.x == 0)
        out[0] = -(waveres[0] + waveres[1] + waveres[2] + waveres[3]) * 0.25f;
}

extern "C" void kernel_launch(void* const* d_in, const int* in_sizes, int n_in,
                              void* d_out, int out_size, void* d_ws, size_t ws_size,
                              hipStream_t stream) {
    const float* tar = (const float*)d_in[0];
    const float* src = (const float*)d_in[1];
    float* out = (float*)d_out;
    unsigned* mmk = (unsigned*)d_ws;                 // 16 uints of keys
    float* hist = (float*)((char*)d_ws + 64);        // 4*1024 floats

    hipMemsetAsync(mmk, 0xFF, 32, stream);           // min keys <- 0xFFFFFFFF
    hipMemsetAsync(mmk + 8, 0x00, 32, stream);       // max keys <- 0
    hipMemsetAsync(hist, 0, N_SAMPLES * 1024 * sizeof(float), stream);
    minmax_kernel<<<dim3(MMBLK, N_SAMPLES), 256, 0, stream>>>(tar, src, mmk);
    hist_mfma<<<dim3(NBLK, N_SAMPLES), 256, 0, stream>>>(tar, src, mmk, hist);
    finalize_kernel<<<1, 256, 0, stream>>>(hist, out);
}

// Round 5
// 112.051 us; speedup vs baseline: 5.1648x; 1.4509x over previous
//
#include <hip/hip_runtime.h>
#include <hip/hip_cooperative_groups.h>
#include <math.h>

namespace cg = cooperative_groups;

#define N_SAMPLES 4
#define P_ELEMS   (96*96*96)          // 884736
#define BPS       216                 // blocks per sample
#define NBLOCKS   (N_SAMPLES * BPS)   // 864  (<= 256 CUs * 4 blocks/CU)
#define TILE      4096                // elements per block per array
#define T4        (TILE/4)            // 1024 float4; 4 per thread per array
// weight = exp(-(xb-k)^2 * 2048/961) = exp2(-((xb-k)*WS)^2), WS = sqrt(2048/961*log2 e)
#define WS        1.75343855f
#define EPSR      1e-10f

typedef __attribute__((ext_vector_type(8)))  short short8;
typedef __attribute__((ext_vector_type(16))) float float16;

// ---------------- shared device phases ----------------

__device__ __forceinline__ void load_chunk(const float* __restrict__ tar,
                                           const float* __restrict__ src,
                                           int n, int j, int t,
                                           float4 a[4], float4 b[4]) {
    const float4* t4 = (const float4*)(tar + (size_t)n * P_ELEMS) + (size_t)j * T4;
    const float4* s4 = (const float4*)(src + (size_t)n * P_ELEMS) + (size_t)j * T4;
    a[0] = t4[t]; a[1] = t4[t + 256]; a[2] = t4[t + 512]; a[3] = t4[t + 768];
    b[0] = s4[t]; b[1] = s4[t + 256]; b[2] = s4[t + 512]; b[3] = s4[t + 768];
}

// block minmax of the register-held chunk; result valid on t==0 only
__device__ __forceinline__ float4 block_minmax(const float4 a[4], const float4 b[4],
                                               int t, float4* sred) {
    float mnt = INFINITY, mxt = -INFINITY, mns = INFINITY, mxs = -INFINITY;
    #pragma unroll
    for (int r = 0; r < 4; r++) {
        mnt = fminf(mnt, fminf(fminf(a[r].x, a[r].y), fminf(a[r].z, a[r].w)));
        mxt = fmaxf(mxt, fmaxf(fmaxf(a[r].x, a[r].y), fmaxf(a[r].z, a[r].w)));
        mns = fminf(mns, fminf(fminf(b[r].x, b[r].y), fminf(b[r].z, b[r].w)));
        mxs = fmaxf(mxs, fmaxf(fmaxf(b[r].x, b[r].y), fmaxf(b[r].z, b[r].w)));
    }
    #pragma unroll
    for (int o = 32; o; o >>= 1) {
        mnt = fminf(mnt, __shfl_xor(mnt, o));
        mxt = fmaxf(mxt, __shfl_xor(mxt, o));
        mns = fminf(mns, __shfl_xor(mns, o));
        mxs = fmaxf(mxs, __shfl_xor(mxs, o));
    }
    int lane = t & 63, wave = t >> 6;
    if (lane == 0) sred[wave] = make_float4(mnt, mxt, mns, mxs);
    __syncthreads();
    float4 r = make_float4(0.f, 0.f, 0.f, 0.f);
    if (t == 0) {
        float4 v0 = sred[0], v1 = sred[1], v2 = sred[2], v3 = sred[3];
        r.x = fminf(fminf(v0.x, v1.x), fminf(v2.x, v3.x));
        r.y = fmaxf(fmaxf(v0.y, v1.y), fmaxf(v2.y, v3.y));
        r.z = fminf(fminf(v0.z, v1.z), fminf(v2.z, v3.z));
        r.w = fmaxf(fmaxf(v0.w, v1.w), fmaxf(v2.w, v3.w));
    }
    return r;
}

// reduce BPS per-block partials of one sample; result broadcast to all threads
__device__ __forceinline__ float4 reduce_partials(const float4* __restrict__ pwn,
                                                  int t, float4* sred, float* bc) {
    float mnt = INFINITY, mxt = -INFINITY, mns = INFINITY, mxs = -INFINITY;
    if (t < BPS) {
        float4 v = pwn[t];
        mnt = v.x; mxt = v.y; mns = v.z; mxs = v.w;
    }
    #pragma unroll
    for (int o = 32; o; o >>= 1) {
        mnt = fminf(mnt, __shfl_xor(mnt, o));
        mxt = fmaxf(mxt, __shfl_xor(mxt, o));
        mns = fminf(mns, __shfl_xor(mns, o));
        mxs = fmaxf(mxs, __shfl_xor(mxs, o));
    }
    int lane = t & 63, wave = t >> 6;
    if (lane == 0) sred[wave] = make_float4(mnt, mxt, mns, mxs);
    __syncthreads();
    if (t == 0) {
        float4 v0 = sred[0], v1 = sred[1], v2 = sred[2], v3 = sred[3];
        bc[0] = fminf(fminf(v0.x, v1.x), fminf(v2.x, v3.x));
        bc[1] = fmaxf(fmaxf(v0.y, v1.y), fmaxf(v2.y, v3.y));
        bc[2] = fminf(fminf(v0.z, v1.z), fminf(v2.z, v3.z));
        bc[3] = fmaxf(fmaxf(v0.w, v1.w), fmaxf(v2.w, v3.w));
    }
    __syncthreads();
    return make_float4(bc[0], bc[1], bc[2], bc[3]);
}

// MFMA joint histogram over this block's chunk (coords pre-scaled by WS).
// A-frag: lane (g=lane>>5, c=lane&31) supplies A[c][8g+j], B[8g+j][c], j=0..7.
// C/D: col = lane&31, row = (reg&3) + 8*(reg>>2) + 4*g.  (validated R3, absmax 0)
__device__ __forceinline__ void hist_phase(float* lds,
                                           const float4 a[4], const float4 b[4],
                                           float mnt, float fit, float mns, float fis,
                                           float* __restrict__ histn, int t) {
    #pragma unroll
    for (int r = 0; r < 4; r++) {
        float4 xo, yo;
        xo.x = (a[r].x - mnt) * fit; xo.y = (a[r].y - mnt) * fit;
        xo.z = (a[r].z - mnt) * fit; xo.w = (a[r].w - mnt) * fit;
        yo.x = (b[r].x - mns) * fis; yo.y = (b[r].y - mns) * fis;
        yo.z = (b[r].z - mns) * fis; yo.w = (b[r].w - mns) * fis;
        ((float4*)lds)[t + r * 256] = xo;
        ((float4*)(lds + TILE))[t + r * 256] = yo;
    }
    __syncthreads();

    int lane = t & 63, wave = t >> 6, g = lane >> 5;
    float q = (float)(lane & 31) * WS;              // pre-scaled bin center
    const float* xb = lds + wave * 1024;
    const float* yb = lds + TILE + wave * 1024;

    float16 acc;
    #pragma unroll
    for (int i = 0; i < 16; i++) acc[i] = 0.0f;

    #pragma unroll 2
    for (int it = 0; it < 64; it++) {               // 16 elements per iteration
        int kb = it * 16 + g * 8;
        float4 xa = *(const float4*)(xb + kb);
        float4 xc = *(const float4*)(xb + kb + 4);
        float4 ya = *(const float4*)(yb + kb);
        float4 yc = *(const float4*)(yb + kb + 4);
        float xs[8] = {xa.x, xa.y, xa.z, xa.w, xc.x, xc.y, xc.z, xc.w};
        float ys[8] = {ya.x, ya.y, ya.z, ya.w, yc.x, yc.y, yc.z, yc.w};
        unsigned av[8], bv[8];
        #pragma unroll
        for (int jj = 0; jj < 8; jj++) {
            float d = xs[jj] - q;
            float arg = -d * d;                     // exp2(-(d*WS)^2) form
            float w;
            asm("v_exp_f32 %0, %1" : "=v"(w) : "v"(arg));
            av[jj] = __float_as_uint(w);
            d = ys[jj] - q;
            arg = -d * d;
            asm("v_exp_f32 %0, %1" : "=v"(w) : "v"(arg));
            bv[jj] = __float_as_uint(w);
        }
        union { unsigned u[4]; short8 v; } af, bf;
        #pragma unroll
        for (int jj = 0; jj < 4; jj++) {            // pack hi16 (bf16 trunc) pairs
            af.u[jj] = __builtin_amdgcn_perm(av[2 * jj + 1], av[2 * jj], 0x07060302u);
            bf.u[jj] = __builtin_amdgcn_perm(bv[2 * jj + 1], bv[2 * jj], 0x07060302u);
        }
        acc = __builtin_amdgcn_mfma_f32_32x32x16_bf16(af.v, bf.v, acc, 0, 0, 0);
    }

    __syncthreads();
    {
        float* hw = lds + wave * 1024;
        int col = lane & 31;
        #pragma unroll
        for (int reg = 0; reg < 16; reg++) {
            int row = (reg & 3) + 8 * (reg >> 2) + 4 * g;
            hw[row * 32 + col] = acc[reg];
        }
    }
    __syncthreads();
    for (int bb = t; bb < 1024; bb += 256) {
        float v = lds[bb] + lds[1024 + bb] + lds[2048 + bb] + lds[3072 + bb];
        unsafeAtomicAdd(&histn[bb], v);
    }
}

// entropies + loss; needs 256 threads and sh[4096]; validated R3
__device__ __forceinline__ void finalize_phase(const float* __restrict__ hist,
                                               float* sh, float* __restrict__ out, int t) {
    __shared__ float wres[4];
    int lane = t & 63, nn = t >> 6;
    const float4* h4 = (const float4*)(hist + nn * 1024);
    float4 h[4];
    float part = 0.0f;
    #pragma unroll
    for (int r = 0; r < 4; r++) {
        h[r] = h4[lane * 4 + r];
        part += (h[r].x + h[r].y) + (h[r].z + h[r].w);
    }
    #pragma unroll
    for (int o = 32; o; o >>= 1) part += __shfl_xor(part, o);
    float inv = 1.0f / part;
    float ej = 0.0f;
    #pragma unroll
    for (int r = 0; r < 4; r++) {
        float4 p;
        p.x = h[r].x * inv; p.y = h[r].y * inv; p.z = h[r].z * inv; p.w = h[r].w * inv;
        ((float4*)(sh + nn * 1024))[lane * 4 + r] = p;
        ej -= p.x * __logf(p.x + EPSR) + p.y * __logf(p.y + EPSR)
            + p.z * __logf(p.z + EPSR) + p.w * __logf(p.w + EPSR);
    }
    #pragma unroll
    for (int o = 32; o; o >>= 1) ej += __shfl_xor(ej, o);
    __syncthreads();
    float m = 0.0f;
    if (lane < 32) {
        int row = lane;
        for (int jj = 0; jj < 32; jj++) m += sh[nn * 1024 + row * 32 + ((jj + row) & 31)];
    } else {
        int col = lane - 32;
        for (int i = 0; i < 32; i++) m += sh[nn * 1024 + i * 32 + col];
    }
    float rc = -m * __logf(m + EPSR);
    #pragma unroll
    for (int o = 16; o; o >>= 1) rc += __shfl_xor(rc, o);   // halves reduce separately
    float es = __shfl(rc, 32);
    if (lane == 0) wres[nn] = (rc + es) / ej;
    __syncthreads();
    if (t == 0)
        out[0] = -(wres[0] + wres[1] + wres[2] + wres[3]) * 0.25f;
}

// ---------------- cooperative fused kernel ----------------

__global__ void __launch_bounds__(256, 4)
mi_fused(const float* __restrict__ tar, const float* __restrict__ src,
         float4* __restrict__ pw, float* __restrict__ hist,
         float* __restrict__ out) {
    cg::grid_group grid = cg::this_grid();
    __shared__ __align__(16) float lds[2 * TILE];   // 32 KB
    __shared__ float4 sred[4];
    __shared__ float bc[4];

    int bid = blockIdx.x;
    int n = bid / BPS, j = bid - n * BPS;
    int t = threadIdx.x;

    float4 a[4], b[4];
    load_chunk(tar, src, n, j, t, a, b);
    float4 mm = block_minmax(a, b, t, sred);
    if (t == 0) pw[bid] = mm;
    if (bid < 16) hist[bid * 256 + t] = 0.0f;
    grid.sync();

    float4 M = reduce_partials(pw + n * BPS, t, sred, bc);
    float fit = 31.0f * WS / (M.y - M.x + 1e-12f);
    float fis = 31.0f * WS / (M.w - M.z + 1e-12f);
    hist_phase(lds, a, b, M.x, fit, M.z, fis, hist + n * 1024, t);
    grid.sync();

    if (bid == 0) finalize_phase(hist, lds, out, t);
}

// ---------------- fallback pipeline (3 dispatches, no memsets) ----------------

__global__ void __launch_bounds__(256, 4)
k_minmax(const float* __restrict__ tar, const float* __restrict__ src,
         float4* __restrict__ pw, float* __restrict__ hist) {
    __shared__ float4 sred[4];
    int n = blockIdx.y, j = blockIdx.x, bid = n * BPS + j;
    int t = threadIdx.x;
    float4 a[4], b[4];
    load_chunk(tar, src, n, j, t, a, b);
    float4 mm = block_minmax(a, b, t, sred);
    if (t == 0) pw[bid] = mm;
    if (bid < 16) hist[bid * 256 + t] = 0.0f;
}

__global__ void __launch_bounds__(256, 4)
k_hist(const float* __restrict__ tar, const float* __restrict__ src,
       const float4* __restrict__ pw, float* __restrict__ hist) {
    __shared__ __align__(16) float lds[2 * TILE];
    __shared__ float4 sred[4];
    __shared__ float bc[4];
    int n = blockIdx.y, j = blockIdx.x;
    int t = threadIdx.x;
    float4 M = reduce_partials(pw + n * BPS, t, sred, bc);
    float fit = 31.0f * WS / (M.y - M.x + 1e-12f);
    float fis = 31.0f * WS / (M.w - M.z + 1e-12f);
    float4 a[4], b[4];
    load_chunk(tar, src, n, j, t, a, b);
    hist_phase(lds, a, b, M.x, fit, M.z, fis, hist + n * 1024, t);
}

__global__ void __launch_bounds__(256)
k_final(const float* __restrict__ hist, float* __restrict__ out) {
    __shared__ float sh[4096];
    finalize_phase(hist, sh, out, threadIdx.x);
}

extern "C" void kernel_launch(void* const* d_in, const int* in_sizes, int n_in,
                              void* d_out, int out_size, void* d_ws, size_t ws_size,
                              hipStream_t stream) {
    const float* tar = (const float*)d_in[0];
    const float* src = (const float*)d_in[1];
    float* out = (float*)d_out;
    float4* pw = (float4*)d_ws;                              // 864 * 16 B
    float* hist = (float*)((char*)d_ws + NBLOCKS * 16);      // 4*1024 floats

    // Host-side (capture-safe) co-residency check; cooperative if it fits.
    int occ = 0, ncu = 0, dev = 0;
    hipError_t qe = hipOccupancyMaxActiveBlocksPerMultiprocessor(&occ, mi_fused, 256, 0);
    hipGetDevice(&dev);
    hipDeviceGetAttribute(&ncu, hipDeviceAttributeMultiprocessorCount, dev);
    bool coop_ok = (qe == hipSuccess) && (ncu > 0) && ((long)occ * ncu >= NBLOCKS);

    if (coop_ok) {
        void* args[] = { (void*)&tar, (void*)&src, (void*)&pw, (void*)&hist, (void*)&out };
        hipError_t e = hipLaunchCooperativeKernel((void*)mi_fused, dim3(NBLOCKS), dim3(256),
                                                  args, 0, stream);
        if (e == hipSuccess) return;
    }
    // Fallback: 3 ordered dispatches, same math.
    k_minmax<<<dim3(BPS, N_SAMPLES), 256, 0, stream>>>(tar, src, pw, hist);
    k_hist<<<dim3(BPS, N_SAMPLES), 256, 0, stream>>>(tar, src, pw, hist);
    k_final<<<1, 256, 0, stream>>>(hist, out);
}

// Round 6
// 111.860 us; speedup vs baseline: 5.1736x; 1.0017x over previous
//
#include <hip/hip_runtime.h>
#include <hip/hip_cooperative_groups.h>
#include <math.h>

namespace cg = cooperative_groups;

#define N_SAMPLES 4
#define P_ELEMS   (96*96*96)          // 884736
#define BPS       432                 // blocks per sample
#define NBLOCKS   (N_SAMPLES * BPS)   // 1728  (<= 256 CUs * 8 blocks/CU)
#define TILE      2048                // elements per block per array
#define T4        (TILE/4)            // 512 float4; 2 per thread per array
// weight = exp(-(xb-k)^2 * 2048/961) = exp2(-((xb-k)*WS)^2), WS = sqrt(2048/961*log2 e)
#define WS        1.75343855f
#define EPSR      1e-10f

typedef __attribute__((ext_vector_type(8)))  short short8;
typedef __attribute__((ext_vector_type(16))) float float16;

// ---------------- shared device phases ----------------

__device__ __forceinline__ void load_chunk(const float* __restrict__ tar,
                                           const float* __restrict__ src,
                                           int n, int j, int t,
                                           float4 a[2], float4 b[2]) {
    const float4* t4 = (const float4*)(tar + (size_t)n * P_ELEMS) + (size_t)j * T4;
    const float4* s4 = (const float4*)(src + (size_t)n * P_ELEMS) + (size_t)j * T4;
    a[0] = t4[t]; a[1] = t4[t + 256];
    b[0] = s4[t]; b[1] = s4[t + 256];
}

// block minmax of the register-held chunk; result valid on t==0 only
__device__ __forceinline__ float4 block_minmax(const float4 a[2], const float4 b[2],
                                               int t, float4* sred) {
    float mnt = INFINITY, mxt = -INFINITY, mns = INFINITY, mxs = -INFINITY;
    #pragma unroll
    for (int r = 0; r < 2; r++) {
        mnt = fminf(mnt, fminf(fminf(a[r].x, a[r].y), fminf(a[r].z, a[r].w)));
        mxt = fmaxf(mxt, fmaxf(fmaxf(a[r].x, a[r].y), fmaxf(a[r].z, a[r].w)));
        mns = fminf(mns, fminf(fminf(b[r].x, b[r].y), fminf(b[r].z, b[r].w)));
        mxs = fmaxf(mxs, fmaxf(fmaxf(b[r].x, b[r].y), fmaxf(b[r].z, b[r].w)));
    }
    #pragma unroll
    for (int o = 32; o; o >>= 1) {
        mnt = fminf(mnt, __shfl_xor(mnt, o));
        mxt = fmaxf(mxt, __shfl_xor(mxt, o));
        mns = fminf(mns, __shfl_xor(mns, o));
        mxs = fmaxf(mxs, __shfl_xor(mxs, o));
    }
    int lane = t & 63, wave = t >> 6;
    if (lane == 0) sred[wave] = make_float4(mnt, mxt, mns, mxs);
    __syncthreads();
    float4 r = make_float4(0.f, 0.f, 0.f, 0.f);
    if (t == 0) {
        float4 v0 = sred[0], v1 = sred[1], v2 = sred[2], v3 = sred[3];
        r.x = fminf(fminf(v0.x, v1.x), fminf(v2.x, v3.x));
        r.y = fmaxf(fmaxf(v0.y, v1.y), fmaxf(v2.y, v3.y));
        r.z = fminf(fminf(v0.z, v1.z), fminf(v2.z, v3.z));
        r.w = fmaxf(fmaxf(v0.w, v1.w), fmaxf(v2.w, v3.w));
    }
    return r;
}

// reduce BPS per-block partials of one sample; result broadcast to all threads
__device__ __forceinline__ float4 reduce_partials(const float4* __restrict__ pwn,
                                                  int t, float4* sred, float* bc) {
    float mnt = INFINITY, mxt = -INFINITY, mns = INFINITY, mxs = -INFINITY;
    for (int i = t; i < BPS; i += 256) {
        float4 v = pwn[i];
        mnt = fminf(mnt, v.x); mxt = fmaxf(mxt, v.y);
        mns = fminf(mns, v.z); mxs = fmaxf(mxs, v.w);
    }
    #pragma unroll
    for (int o = 32; o; o >>= 1) {
        mnt = fminf(mnt, __shfl_xor(mnt, o));
        mxt = fmaxf(mxt, __shfl_xor(mxt, o));
        mns = fminf(mns, __shfl_xor(mns, o));
        mxs = fmaxf(mxs, __shfl_xor(mxs, o));
    }
    int lane = t & 63, wave = t >> 6;
    if (lane == 0) sred[wave] = make_float4(mnt, mxt, mns, mxs);
    __syncthreads();
    if (t == 0) {
        float4 v0 = sred[0], v1 = sred[1], v2 = sred[2], v3 = sred[3];
        bc[0] = fminf(fminf(v0.x, v1.x), fminf(v2.x, v3.x));
        bc[1] = fmaxf(fmaxf(v0.y, v1.y), fmaxf(v2.y, v3.y));
        bc[2] = fminf(fminf(v0.z, v1.z), fminf(v2.z, v3.z));
        bc[3] = fmaxf(fmaxf(v0.w, v1.w), fmaxf(v2.w, v3.w));
    }
    __syncthreads();
    return make_float4(bc[0], bc[1], bc[2], bc[3]);
}

// MFMA joint histogram over this block's chunk (coords pre-scaled by WS).
// A-frag: lane (g=lane>>5, c=lane&31) supplies A[c][8g+j], B[8g+j][c], j=0..7.
// C/D: col = lane&31, row = (reg&3) + 8*(reg>>2) + 4*g.  (validated R3/R5, absmax 0)
__device__ __forceinline__ void hist_phase(float* lds,
                                           const float4 a[2], const float4 b[2],
                                           float mnt, float fit, float mns, float fis,
                                           float* __restrict__ histn, int t) {
    #pragma unroll
    for (int r = 0; r < 2; r++) {
        float4 xo, yo;
        xo.x = (a[r].x - mnt) * fit; xo.y = (a[r].y - mnt) * fit;
        xo.z = (a[r].z - mnt) * fit; xo.w = (a[r].w - mnt) * fit;
        yo.x = (b[r].x - mns) * fis; yo.y = (b[r].y - mns) * fis;
        yo.z = (b[r].z - mns) * fis; yo.w = (b[r].w - mns) * fis;
        ((float4*)lds)[t + r * 256] = xo;
        ((float4*)(lds + TILE))[t + r * 256] = yo;
    }
    __syncthreads();

    int lane = t & 63, wave = t >> 6, g = lane >> 5;
    float q = (float)(lane & 31) * WS;              // pre-scaled bin center
    const float* xb = lds + wave * (TILE / 4);      // 512 elements per wave
    const float* yb = lds + TILE + wave * (TILE / 4);

    float16 acc;
    #pragma unroll
    for (int i = 0; i < 16; i++) acc[i] = 0.0f;

    #pragma unroll 4
    for (int it = 0; it < TILE / 4 / 16; it++) {    // 32 iterations, 16 elements each
        int kb = it * 16 + g * 8;
        float4 xa = *(const float4*)(xb + kb);
        float4 xc = *(const float4*)(xb + kb + 4);
        float4 ya = *(const float4*)(yb + kb);
        float4 yc = *(const float4*)(yb + kb + 4);
        float xs[8] = {xa.x, xa.y, xa.z, xa.w, xc.x, xc.y, xc.z, xc.w};
        float ys[8] = {ya.x, ya.y, ya.z, ya.w, yc.x, yc.y, yc.z, yc.w};
        unsigned av[8], bv[8];
        #pragma unroll
        for (int jj = 0; jj < 8; jj++) {
            float d = xs[jj] - q;
            float arg = -d * d;                     // exp2(-(d*WS)^2) form
            float w;
            asm("v_exp_f32 %0, %1" : "=v"(w) : "v"(arg));
            av[jj] = __float_as_uint(w);
            d = ys[jj] - q;
            arg = -d * d;
            asm("v_exp_f32 %0, %1" : "=v"(w) : "v"(arg));
            bv[jj] = __float_as_uint(w);
        }
        union { unsigned u[4]; short8 v; } af, bf;
        #pragma unroll
        for (int jj = 0; jj < 4; jj++) {            // pack hi16 (bf16 trunc) pairs
            af.u[jj] = __builtin_amdgcn_perm(av[2 * jj + 1], av[2 * jj], 0x07060302u);
            bf.u[jj] = __builtin_amdgcn_perm(bv[2 * jj + 1], bv[2 * jj], 0x07060302u);
        }
        acc = __builtin_amdgcn_mfma_f32_32x32x16_bf16(af.v, bf.v, acc, 0, 0, 0);
    }

    __syncthreads();
    {
        float* hw = lds + wave * 1024;              // 4 waves x 1024 = 4096 = 2*TILE
        int col = lane & 31;
        #pragma unroll
        for (int reg = 0; reg < 16; reg++) {
            int row = (reg & 3) + 8 * (reg >> 2) + 4 * g;
            hw[row * 32 + col] = acc[reg];
        }
    }
    __syncthreads();
    for (int bb = t; bb < 1024; bb += 256) {
        float v = lds[bb] + lds[1024 + bb] + lds[2048 + bb] + lds[3072 + bb];
        unsafeAtomicAdd(&histn[bb], v);
    }
}

// entropies + loss; needs 256 threads and sh[4096]; validated R3/R5
__device__ __forceinline__ void finalize_phase(const float* __restrict__ hist,
                                               float* sh, float* __restrict__ out, int t) {
    __shared__ float wres[4];
    int lane = t & 63, nn = t >> 6;
    const float4* h4 = (const float4*)(hist + nn * 1024);
    float4 h[4];
    float part = 0.0f;
    #pragma unroll
    for (int r = 0; r < 4; r++) {
        h[r] = h4[lane * 4 + r];
        part += (h[r].x + h[r].y) + (h[r].z + h[r].w);
    }
    #pragma unroll
    for (int o = 32; o; o >>= 1) part += __shfl_xor(part, o);
    float inv = 1.0f / part;
    float ej = 0.0f;
    #pragma unroll
    for (int r = 0; r < 4; r++) {
        float4 p;
        p.x = h[r].x * inv; p.y = h[r].y * inv; p.z = h[r].z * inv; p.w = h[r].w * inv;
        ((float4*)(sh + nn * 1024))[lane * 4 + r] = p;
        ej -= p.x * __logf(p.x + EPSR) + p.y * __logf(p.y + EPSR)
            + p.z * __logf(p.z + EPSR) + p.w * __logf(p.w + EPSR);
    }
    #pragma unroll
    for (int o = 32; o; o >>= 1) ej += __shfl_xor(ej, o);
    __syncthreads();
    float m = 0.0f;
    if (lane < 32) {
        int row = lane;
        for (int jj = 0; jj < 32; jj++) m += sh[nn * 1024 + row * 32 + ((jj + row) & 31)];
    } else {
        int col = lane - 32;
        for (int i = 0; i < 32; i++) m += sh[nn * 1024 + i * 32 + col];
    }
    float rc = -m * __logf(m + EPSR);
    #pragma unroll
    for (int o = 16; o; o >>= 1) rc += __shfl_xor(rc, o);   // halves reduce separately
    float es = __shfl(rc, 32);
    if (lane == 0) wres[nn] = (rc + es) / ej;
    __syncthreads();
    if (t == 0)
        out[0] = -(wres[0] + wres[1] + wres[2] + wres[3]) * 0.25f;
}

// ---------------- cooperative fused kernel ----------------

__global__ void __launch_bounds__(256, 8)
mi_fused(const float* __restrict__ tar, const float* __restrict__ src,
         float4* __restrict__ pw, float* __restrict__ hist,
         float* __restrict__ out) {
    cg::grid_group grid = cg::this_grid();
    __shared__ __align__(16) float lds[2 * TILE];   // 16 KB
    __shared__ float4 sred[4];
    __shared__ float bc[4];

    int bid = blockIdx.x;
    int n = bid / BPS, j = bid - n * BPS;
    int t = threadIdx.x;

    float4 a[2], b[2];
    load_chunk(tar, src, n, j, t, a, b);
    float4 mm = block_minmax(a, b, t, sred);
    if (t == 0) pw[bid] = mm;
    if (bid < 16) hist[bid * 256 + t] = 0.0f;
    grid.sync();

    float4 M = reduce_partials(pw + n * BPS, t, sred, bc);
    float fit = 31.0f * WS / (M.y - M.x + 1e-12f);
    float fis = 31.0f * WS / (M.w - M.z + 1e-12f);
    hist_phase(lds, a, b, M.x, fit, M.z, fis, hist + n * 1024, t);
    grid.sync();

    if (bid == 0) finalize_phase(hist, lds, out, t);
}

// ---------------- fallback pipeline (3 dispatches, no memsets) ----------------

__global__ void __launch_bounds__(256, 8)
k_minmax(const float* __restrict__ tar, const float* __restrict__ src,
         float4* __restrict__ pw, float* __restrict__ hist) {
    __shared__ float4 sred[4];
    int n = blockIdx.y, j = blockIdx.x, bid = n * BPS + j;
    int t = threadIdx.x;
    float4 a[2], b[2];
    load_chunk(tar, src, n, j, t, a, b);
    float4 mm = block_minmax(a, b, t, sred);
    if (t == 0) pw[bid] = mm;
    if (bid < 16) hist[bid * 256 + t] = 0.0f;
}

__global__ void __launch_bounds__(256, 8)
k_hist(const float* __restrict__ tar, const float* __restrict__ src,
       const float4* __restrict__ pw, float* __restrict__ hist) {
    __shared__ __align__(16) float lds[2 * TILE];
    __shared__ float4 sred[4];
    __shared__ float bc[4];
    int n = blockIdx.y, j = blockIdx.x;
    int t = threadIdx.x;
    float4 M = reduce_partials(pw + n * BPS, t, sred, bc);
    float fit = 31.0f * WS / (M.y - M.x + 1e-12f);
    float fis = 31.0f * WS / (M.w - M.z + 1e-12f);
    float4 a[2], b[2];
    load_chunk(tar, src, n, j, t, a, b);
    hist_phase(lds, a, b, M.x, fit, M.z, fis, hist + n * 1024, t);
}

__global__ void __launch_bounds__(256)
k_final(const float* __restrict__ hist, float* __restrict__ out) {
    __shared__ float sh[4096];
    finalize_phase(hist, sh, out, threadIdx.x);
}

extern "C" void kernel_launch(void* const* d_in, const int* in_sizes, int n_in,
                              void* d_out, int out_size, void* d_ws, size_t ws_size,
                              hipStream_t stream) {
    const float* tar = (const float*)d_in[0];
    const float* src = (const float*)d_in[1];
    float* out = (float*)d_out;
    float4* pw = (float4*)d_ws;                              // 1728 * 16 B
    float* hist = (float*)((char*)d_ws + NBLOCKS * 16);      // 4*1024 floats

    // Host-side (capture-safe) co-residency check; cooperative if it fits.
    int occ = 0, ncu = 0, dev = 0;
    hipError_t qe = hipOccupancyMaxActiveBlocksPerMultiprocessor(&occ, mi_fused, 256, 0);
    hipGetDevice(&dev);
    hipDeviceGetAttribute(&ncu, hipDeviceAttributeMultiprocessorCount, dev);
    bool coop_ok = (qe == hipSuccess) && (ncu > 0) && ((long)occ * ncu >= NBLOCKS);

    if (coop_ok) {
        void* args[] = { (void*)&tar, (void*)&src, (void*)&pw, (void*)&hist, (void*)&out };
        hipError_t e = hipLaunchCooperativeKernel((void*)mi_fused, dim3(NBLOCKS), dim3(256),
                                                  args, 0, stream);
        if (e == hipSuccess) return;
    }
    // Fallback: 3 ordered dispatches, same math.
    k_minmax<<<dim3(BPS, N_SAMPLES), 256, 0, stream>>>(tar, src, pw, hist);
    k_hist<<<dim3(BPS, N_SAMPLES), 256, 0, stream>>>(tar, src, pw, hist);
    k_final<<<1, 256, 0, stream>>>(hist, out);
}

// Round 7
// 111.562 us; speedup vs baseline: 5.1874x; 1.0027x over previous
//
#include <hip/hip_runtime.h>
#include <math.h>

#define N_SAMPLES 4
#define P_ELEMS   (96*96*96)          // 884736
// minmax geometry: deep loads, pure BW
#define MM_BPS    216
#define MM_T4     1024                // float4 per array per block (4/thread)
// hist geometry: validated R6 MFMA loop
#define H_BPS     432
#define H_TILE    2048
#define H_T4      (H_TILE/4)          // 512 float4; 2 per thread per array
#define NCOPY     8                   // replicated global hists (contention / XCD spread)
// weight = exp(-(xb-k)^2 * 2048/961) = exp2(-((xb-k)*WS)^2), WS = sqrt(2048/961*log2 e)
#define WS        1.75343855f
#define EPSR      1e-10f

typedef __attribute__((ext_vector_type(8)))  short short8;
typedef __attribute__((ext_vector_type(16))) float float16;

// ws: pw[1728] float4 ; hist[NCOPY][4][1024] floats
#define PW_COUNT  (N_SAMPLES * H_BPS)

// ---------------- dispatch 1: per-block minmax partials + hist zeroing ----------------

__global__ void __launch_bounds__(256)
k_minmax(const float* __restrict__ tar, const float* __restrict__ src,
         float4* __restrict__ pw, float* __restrict__ histall) {
    __shared__ float4 sred[4];
    int n = blockIdx.y, j = blockIdx.x;
    int t = threadIdx.x;
    const float4* t4 = (const float4*)(tar + (size_t)n * P_ELEMS) + (size_t)j * MM_T4;
    const float4* s4 = (const float4*)(src + (size_t)n * P_ELEMS) + (size_t)j * MM_T4;
    float4 a0 = t4[t], a1 = t4[t + 256], a2 = t4[t + 512], a3 = t4[t + 768];
    float4 b0 = s4[t], b1 = s4[t + 256], b2 = s4[t + 512], b3 = s4[t + 768];
    float mnt = fminf(fminf(fminf(a0.x, a0.y), fminf(a0.z, a0.w)),
                      fminf(fminf(a1.x, a1.y), fminf(a1.z, a1.w)));
    mnt = fminf(mnt, fminf(fminf(fminf(a2.x, a2.y), fminf(a2.z, a2.w)),
                           fminf(fminf(a3.x, a3.y), fminf(a3.z, a3.w))));
    float mxt = fmaxf(fmaxf(fmaxf(a0.x, a0.y), fmaxf(a0.z, a0.w)),
                      fmaxf(fmaxf(a1.x, a1.y), fmaxf(a1.z, a1.w)));
    mxt = fmaxf(mxt, fmaxf(fmaxf(fmaxf(a2.x, a2.y), fmaxf(a2.z, a2.w)),
                           fmaxf(fmaxf(a3.x, a3.y), fmaxf(a3.z, a3.w))));
    float mns = fminf(fminf(fminf(b0.x, b0.y), fminf(b0.z, b0.w)),
                      fminf(fminf(b1.x, b1.y), fminf(b1.z, b1.w)));
    mns = fminf(mns, fminf(fminf(fminf(b2.x, b2.y), fminf(b2.z, b2.w)),
                           fminf(fminf(b3.x, b3.y), fminf(b3.z, b3.w))));
    float mxs = fmaxf(fmaxf(fmaxf(b0.x, b0.y), fmaxf(b0.z, b0.w)),
                      fmaxf(fmaxf(b1.x, b1.y), fmaxf(b1.z, b1.w)));
    mxs = fmaxf(mxs, fmaxf(fmaxf(fmaxf(b2.x, b2.y), fmaxf(b2.z, b2.w)),
                           fmaxf(fmaxf(b3.x, b3.y), fmaxf(b3.z, b3.w))));
    #pragma unroll
    for (int o = 32; o; o >>= 1) {
        mnt = fminf(mnt, __shfl_xor(mnt, o));
        mxt = fmaxf(mxt, __shfl_xor(mxt, o));
        mns = fminf(mns, __shfl_xor(mns, o));
        mxs = fmaxf(mxs, __shfl_xor(mxs, o));
    }
    int lane = t & 63, wave = t >> 6;
    if (lane == 0) sred[wave] = make_float4(mnt, mxt, mns, mxs);
    __syncthreads();
    // each mm-block covers two hist-blocks' ranges; store the same partial to both slots
    if (t == 0) {
        float4 v0 = sred[0], v1 = sred[1], v2 = sred[2], v3 = sred[3];
        float4 r;
        r.x = fminf(fminf(v0.x, v1.x), fminf(v2.x, v3.x));
        r.y = fmaxf(fmaxf(v0.y, v1.y), fmaxf(v2.y, v3.y));
        r.z = fminf(fminf(v0.z, v1.z), fminf(v2.z, v3.z));
        r.w = fmaxf(fmaxf(v0.w, v1.w), fmaxf(v2.w, v3.w));
        pw[n * MM_BPS + j] = r;
    }
    int bid = n * MM_BPS + j;
    if (bid < 128) histall[bid * 256 + t] = 0.0f;    // zero 8*4*1024 floats
}

// ---------------- dispatch 2: MFMA joint histogram ----------------
// A-frag: lane (g=lane>>5, c=lane&31) supplies A[c][8g+j], B[8g+j][c], j=0..7.
// C/D: col = lane&31, row = (reg&3) + 8*(reg>>2) + 4*g.  (validated R3/R5/R6, absmax 0)

__global__ void __launch_bounds__(256, 8)
k_hist(const float* __restrict__ tar, const float* __restrict__ src,
       const float4* __restrict__ pw, float* __restrict__ histall) {
    __shared__ __align__(16) float lds[2 * H_TILE];  // 16 KB
    __shared__ float4 sred[4];
    __shared__ float bc[4];
    int n = blockIdx.y, j = blockIdx.x;
    int t = threadIdx.x;

    // issue the big input loads first; they retire while we reduce partials
    const float4* t4 = (const float4*)(tar + (size_t)n * P_ELEMS) + (size_t)j * H_T4;
    const float4* s4 = (const float4*)(src + (size_t)n * P_ELEMS) + (size_t)j * H_T4;
    float4 a0 = t4[t], a1 = t4[t + 256];
    float4 b0 = s4[t], b1 = s4[t + 256];

    // reduce the sample's 216 minmax partials (L2-hot)
    {
        const float4* pwn = pw + n * MM_BPS;
        float mnt = INFINITY, mxt = -INFINITY, mns = INFINITY, mxs = -INFINITY;
        if (t < MM_BPS) {
            float4 v = pwn[t];
            mnt = v.x; mxt = v.y; mns = v.z; mxs = v.w;
        }
        #pragma unroll
        for (int o = 32; o; o >>= 1) {
            mnt = fminf(mnt, __shfl_xor(mnt, o));
            mxt = fmaxf(mxt, __shfl_xor(mxt, o));
            mns = fminf(mns, __shfl_xor(mns, o));
            mxs = fmaxf(mxs, __shfl_xor(mxs, o));
        }
        int lane = t & 63, wave = t >> 6;
        if (lane == 0) sred[wave] = make_float4(mnt, mxt, mns, mxs);
        __syncthreads();
        if (t == 0) {
            float4 v0 = sred[0], v1 = sred[1], v2 = sred[2], v3 = sred[3];
            bc[0] = fminf(fminf(v0.x, v1.x), fminf(v2.x, v3.x));
            bc[1] = fmaxf(fmaxf(v0.y, v1.y), fmaxf(v2.y, v3.y));
            bc[2] = fminf(fminf(v0.z, v1.z), fminf(v2.z, v3.z));
            bc[3] = fmaxf(fmaxf(v0.w, v1.w), fmaxf(v2.w, v3.w));
        }
        __syncthreads();
    }
    float mnt = bc[0], mns = bc[2];
    float fit = 31.0f * WS / (bc[1] - mnt + 1e-12f);
    float fis = 31.0f * WS / (bc[3] - mns + 1e-12f);

    // stage pre-scaled bin coords
    {
        float4 xo, yo;
        xo.x = (a0.x - mnt) * fit; xo.y = (a0.y - mnt) * fit;
        xo.z = (a0.z - mnt) * fit; xo.w = (a0.w - mnt) * fit;
        ((float4*)lds)[t] = xo;
        xo.x = (a1.x - mnt) * fit; xo.y = (a1.y - mnt) * fit;
        xo.z = (a1.z - mnt) * fit; xo.w = (a1.w - mnt) * fit;
        ((float4*)lds)[t + 256] = xo;
        yo.x = (b0.x - mns) * fis; yo.y = (b0.y - mns) * fis;
        yo.z = (b0.z - mns) * fis; yo.w = (b0.w - mns) * fis;
        ((float4*)(lds + H_TILE))[t] = yo;
        yo.x = (b1.x - mns) * fis; yo.y = (b1.y - mns) * fis;
        yo.z = (b1.z - mns) * fis; yo.w = (b1.w - mns) * fis;
        ((float4*)(lds + H_TILE))[t + 256] = yo;
    }
    __syncthreads();

    int lane = t & 63, wave = t >> 6, g = lane >> 5;
    float q = (float)(lane & 31) * WS;
    const float* xb = lds + wave * (H_TILE / 4);
    const float* yb = lds + H_TILE + wave * (H_TILE / 4);

    float16 acc;
    #pragma unroll
    for (int i = 0; i < 16; i++) acc[i] = 0.0f;

    #pragma unroll 4
    for (int it = 0; it < H_TILE / 4 / 16; it++) {   // 32 iterations, 16 elements each
        int kb = it * 16 + g * 8;
        float4 xa = *(const float4*)(xb + kb);
        float4 xc = *(const float4*)(xb + kb + 4);
        float4 ya = *(const float4*)(yb + kb);
        float4 yc = *(const float4*)(yb + kb + 4);
        float xs[8] = {xa.x, xa.y, xa.z, xa.w, xc.x, xc.y, xc.z, xc.w};
        float ys[8] = {ya.x, ya.y, ya.z, ya.w, yc.x, yc.y, yc.z, yc.w};
        unsigned av[8], bv[8];
        #pragma unroll
        for (int jj = 0; jj < 8; jj++) {
            float d = xs[jj] - q;
            float arg = -d * d;
            float w;
            asm("v_exp_f32 %0, %1" : "=v"(w) : "v"(arg));
            av[jj] = __float_as_uint(w);
            d = ys[jj] - q;
            arg = -d * d;
            asm("v_exp_f32 %0, %1" : "=v"(w) : "v"(arg));
            bv[jj] = __float_as_uint(w);
        }
        union { unsigned u[4]; short8 v; } af, bf;
        #pragma unroll
        for (int jj = 0; jj < 4; jj++) {
            af.u[jj] = __builtin_amdgcn_perm(av[2 * jj + 1], av[2 * jj], 0x07060302u);
            bf.u[jj] = __builtin_amdgcn_perm(bv[2 * jj + 1], bv[2 * jj], 0x07060302u);
        }
        acc = __builtin_amdgcn_mfma_f32_32x32x16_bf16(af.v, bf.v, acc, 0, 0, 0);
    }

    __syncthreads();
    {
        float* hw = lds + wave * 1024;
        int col = lane & 31;
        #pragma unroll
        for (int reg = 0; reg < 16; reg++) {
            int row = (reg & 3) + 8 * (reg >> 2) + 4 * g;
            hw[row * 32 + col] = acc[reg];
        }
    }
    __syncthreads();
    // merge into one of NCOPY replicated hists (spread over XCD round-robin)
    float* histn = histall + ((j & (NCOPY - 1)) * N_SAMPLES + n) * 1024;
    for (int bb = t; bb < 1024; bb += 256) {
        float v = lds[bb] + lds[1024 + bb] + lds[2048 + bb] + lds[3072 + bb];
        unsafeAtomicAdd(&histn[bb], v);
    }
}

// ---------------- dispatch 3: entropies + loss ----------------

__global__ void __launch_bounds__(256)
k_final(const float* __restrict__ histall, float* __restrict__ out) {
    __shared__ float sh[4096];
    __shared__ float wres[4];
    int t = threadIdx.x;
    int lane = t & 63, nn = t >> 6;
    float4 h[4];
    float part = 0.0f;
    #pragma unroll
    for (int r = 0; r < 4; r++) {
        float4 s = make_float4(0.f, 0.f, 0.f, 0.f);
        #pragma unroll
        for (int c = 0; c < NCOPY; c++) {
            const float4* h4 = (const float4*)(histall + (c * N_SAMPLES + nn) * 1024);
            float4 v = h4[lane * 4 + r];
            s.x += v.x; s.y += v.y; s.z += v.z; s.w += v.w;
        }
        h[r] = s;
        part += (s.x + s.y) + (s.z + s.w);
    }
    #pragma unroll
    for (int o = 32; o; o >>= 1) part += __shfl_xor(part, o);
    float inv = 1.0f / part;
    float ej = 0.0f;
    #pragma unroll
    for (int r = 0; r < 4; r++) {
        float4 p;
        p.x = h[r].x * inv; p.y = h[r].y * inv; p.z = h[r].z * inv; p.w = h[r].w * inv;
        ((float4*)(sh + nn * 1024))[lane * 4 + r] = p;
        ej -= p.x * __logf(p.x + EPSR) + p.y * __logf(p.y + EPSR)
            + p.z * __logf(p.z + EPSR) + p.w * __logf(p.w + EPSR);
    }
    #pragma unroll
    for (int o = 32; o; o >>= 1) ej += __shfl_xor(ej, o);
    __syncthreads();
    float m = 0.0f;
    if (lane < 32) {
        int row = lane;
        for (int jj = 0; jj < 32; jj++) m += sh[nn * 1024 + row * 32 + ((jj + row) & 31)];
    } else {
        int col = lane - 32;
        for (int i = 0; i < 32; i++) m += sh[nn * 1024 + i * 32 + col];
    }
    float rc = -m * __logf(m + EPSR);
    #pragma unroll
    for (int o = 16; o; o >>= 1) rc += __shfl_xor(rc, o);   // halves reduce separately
    float es = __shfl(rc, 32);
    if (lane == 0) wres[nn] = (rc + es) / ej;
    __syncthreads();
    if (t == 0)
        out[0] = -(wres[0] + wres[1] + wres[2] + wres[3]) * 0.25f;
}

extern "C" void kernel_launch(void* const* d_in, const int* in_sizes, int n_in,
                              void* d_out, int out_size, void* d_ws, size_t ws_size,
                              hipStream_t stream) {
    const float* tar = (const float*)d_in[0];
    const float* src = (const float*)d_in[1];
    float* out = (float*)d_out;
    float4* pw = (float4*)d_ws;                                  // 864 used (alloc 1728 slots)
    float* histall = (float*)((char*)d_ws + PW_COUNT * 16);      // NCOPY*4*1024 floats

    k_minmax<<<dim3(MM_BPS, N_SAMPLES), 256, 0, stream>>>(tar, src, pw, histall);
    k_hist<<<dim3(H_BPS, N_SAMPLES), 256, 0, stream>>>(tar, src, pw, histall);
    k_final<<<1, 256, 0, stream>>>(histall, out);
}